// Round 5
// baseline (2285.181 us; speedup 1.0000x reference)
//
#include <hip/hip_runtime.h>

typedef unsigned short u16;
typedef unsigned int u32;
typedef __bf16 bf16x8 __attribute__((ext_vector_type(8)));
typedef float f32x4 __attribute__((ext_vector_type(4)));
typedef u16 u16x4 __attribute__((ext_vector_type(4)));
typedef u16 u16x8 __attribute__((ext_vector_type(8)));

#define N_TW 1024
#define L_TOK 64
#define M1 (N_TW * L_TOK)

__device__ __forceinline__ u16 f2bf(float f) {
  u32 u = __builtin_bit_cast(u32, f);
  u += 0x7fffu + ((u >> 16) & 1u);
  return (u16)(u >> 16);
}
__device__ __forceinline__ float bf2f(u16 b) {
  u32 u = ((u32)b) << 16;
  return __builtin_bit_cast(float, u);
}
__device__ __forceinline__ void gl_lds16(const void* g, void* l) {
  __builtin_amdgcn_global_load_lds((const __attribute__((address_space(1))) u32*)g,
                                   (__attribute__((address_space(3))) u32*)l, 16, 0, 0);
}
__device__ __forceinline__ float sigf(float x) { return 1.f / (1.f + __expf(-x)); }
__device__ __forceinline__ float tanh_(float x) { return 1.f - 2.f / (__expf(2.f * x) + 1.f); }

// ---------------- prep: fp32 -> bf16 weight conversion ----------------
__global__ __launch_bounds__(256) void k_f2bf(const float* __restrict__ s, u16* __restrict__ d, int n) {
  int i = (blockIdx.x * 256 + threadIdx.x) * 4;
  if (i < n) {
    float4 v = *(const float4*)(s + i);
    u16x4 o;
    o.x = f2bf(v.x); o.y = f2bf(v.y); o.z = f2bf(v.z); o.w = f2bf(v.w);
    *(u16x4*)(d + i) = o;
  }
}

__global__ __launch_bounds__(256) void k_bias(const float* __restrict__ a, const float* __restrict__ b,
                                              const float* __restrict__ c, const float* __restrict__ d,
                                              float* __restrict__ o) {
  int i = blockIdx.x * 256 + threadIdx.x;  // 0..2047
  o[i] = (i < 1024) ? (a[i] + b[i]) : (c[i - 1024] + d[i - 1024]);
}

// ---------------- Whh permute + pre-swizzle for k_lstm3 ----------------
// WhhP[dir][cb][cc(256)][ke(256)]: cc = g*64 + s*16 + lr -> (gate g, h = cb*64 + s*16 + lr).
// Stored ke holds source k = ke ^ ((cc&7)<<3)  (inverse XOR so linear gl_lds + XOR-read works).
__global__ __launch_bounds__(256) void k_prep_whh(const float* __restrict__ Wf, const float* __restrict__ Wb,
                                                  u16* __restrict__ P) {
  int e = blockIdx.x * 256 + threadIdx.x;  // 0..524287
  int dir = e >> 18;
  int cb = (e >> 16) & 3;
  int cc = (e >> 8) & 255;
  int ke = e & 255;
  int k = ke ^ ((cc & 7) << 3);
  int g = cc >> 6, s = (cc >> 4) & 3, lrr = cc & 15;
  int h = cb * 64 + s * 16 + lrr;
  const float* W = dir ? Wb : Wf;
  P[e] = f2bf(W[(g * 256 + h) * 256 + k]);
}

// ---------------- embedding gather + bf16 convert ----------------
__global__ __launch_bounds__(256) void k_gather(const int* __restrict__ tok, const float* __restrict__ emb,
                                                u16* __restrict__ x) {
  long long t = (long long)blockIdx.x * 256 + threadIdx.x;
  long long base = t * 8;
  int row = (int)(base >> 9);
  int col = (int)(base & 511);
  long long src = (long long)tok[row] * 512 + col;
  float4 a = *(const float4*)(emb + src);
  float4 b = *(const float4*)(emb + src + 4);
  u16x8 o;
  o[0] = f2bf(a.x); o[1] = f2bf(a.y); o[2] = f2bf(a.z); o[3] = f2bf(a.w);
  o[4] = f2bf(b.x); o[5] = f2bf(b.y); o[6] = f2bf(b.z); o[7] = f2bf(b.w);
  *(u16x8*)(x + base) = o;
}

// ---------------- GEMM: xg = X @ Wih^T + bias, written in XGP layout ----------------
// XGP[t][m(2048)][cb(4)][cx(256)], cx = hl*4 + gate, hl = h&63; slot t = dir ? 63-l : l, m = dir*1024+n.
__global__ __launch_bounds__(256) void k_gemm_xg(const u16* __restrict__ X, const u16* __restrict__ W,
                                                 const float* __restrict__ bias, u16* __restrict__ XGP) {
  __shared__ u16 Al[128 * 64];
  __shared__ u16 Bl[128 * 64];
  const int tid = threadIdx.x;
  const int wv = tid >> 6, lane = tid & 63;
  const int lr = lane & 15, lh = lane >> 4;
  const int bid = blockIdx.x;
  const int local = bid >> 3;
  const int bn = local & 15;
  const int bm = (bid & 7) * 64 + (local >> 4);
  f32x4 acc[2][8] = {};
  for (int kt = 0; kt < 8; ++kt) {
#pragma unroll
    for (int r = 0; r < 4; ++r) {
      int chunk = r * 4 + wv;
      int s = chunk * 1024 + lane * 16;
      int row = s >> 7;
      int kb = (s & 127) ^ ((row & 7) << 4);
      gl_lds16(X + (size_t)(bm * 128 + row) * 512 + kt * 64 + (kb >> 1), (char*)Al + chunk * 1024);
      gl_lds16(W + (size_t)(bn * 128 + row) * 512 + kt * 64 + (kb >> 1), (char*)Bl + chunk * 1024);
    }
    __syncthreads();
#pragma unroll
    for (int ks = 0; ks < 2; ++ks) {
      int kbf = ks * 64 + lh * 16;
      int ra = wv * 32 + lr;
      int xa = kbf ^ ((ra & 7) << 4);
      bf16x8 a0 = *(const bf16x8*)((const char*)Al + ra * 128 + xa);
      bf16x8 a1 = *(const bf16x8*)((const char*)Al + (ra + 16) * 128 + xa);
#pragma unroll
      for (int nj = 0; nj < 8; ++nj) {
        int c = nj * 16 + lr;
        bf16x8 b = *(const bf16x8*)((const char*)Bl + c * 128 + (kbf ^ ((c & 7) << 4)));
        acc[0][nj] = __builtin_amdgcn_mfma_f32_16x16x32_bf16(a0, b, acc[0][nj], 0, 0, 0);
        acc[1][nj] = __builtin_amdgcn_mfma_f32_16x16x32_bf16(a1, b, acc[1][nj], 0, 0, 0);
      }
    }
    __syncthreads();
  }
#pragma unroll
  for (int mi = 0; mi < 2; ++mi)
#pragma unroll
    for (int nj = 0; nj < 8; ++nj) {
      int col = bn * 128 + nj * 16 + lr;
      float bv = bias[col];
      int dirg = col >> 10, gg = (col >> 8) & 3, h = col & 255;
#pragma unroll
      for (int r = 0; r < 4; ++r) {
        int row = bm * 128 + wv * 32 + mi * 16 + lh * 4 + r;
        int n = row >> 6, l = row & 63;
        int tt = dirg ? (63 - l) : l;
        int m = dirg * 1024 + n;
        size_t idx = ((size_t)(tt * 2048 + m) * 4 + (h >> 6)) * 256 + (h & 63) * 4 + gg;
        XGP[idx] = f2bf(acc[mi][nj][r] + bv);
      }
    }
}

// ---------------- image mean over 49 positions ----------------
__global__ __launch_bounds__(256) void k_imgmean(const float* __restrict__ img, u16* __restrict__ o) {
  int n = blockIdx.x;
  for (int j = 0; j < 2; ++j) {
    int col = threadIdx.x + j * 256;
    const float* p = img + (long long)n * 49 * 512 + col;
    float s = 0.f;
    for (int r = 0; r < 49; ++r) s += p[r * 512];
    o[(long long)n * 512 + col] = f2bf(s * (1.f / 49.f));
  }
}

// ---------------- image GEMM ----------------
__global__ __launch_bounds__(256) void k_gemm_img(const u16* __restrict__ A, const u16* __restrict__ W,
                                                  const float* __restrict__ bias, float* __restrict__ O) {
  __shared__ u16 Al[128 * 32];
  __shared__ u16 Bl[128 * 32];
  const int tid = threadIdx.x;
  const int wv = tid >> 6, lane = tid & 63;
  const int bm = blockIdx.x, bn = blockIdx.y;
  f32x4 acc[2][8] = {};
  const int lr = lane & 15, lk = (lane >> 4) * 8;
  for (int kt = 0; kt < 16; ++kt) {
    for (int i = 0; i < 2; ++i) {
      int lin = (wv * 2 + i) * 64 + lane;
      int r = lin >> 2, kc = lin & 3;
      int k = kt * 32 + kc * 8;
      gl_lds16(A + (long long)(bm * 128 + r) * 512 + k, &Al[(wv * 2 + i) * 512]);
      gl_lds16(W + (long long)(bn * 128 + r) * 512 + k, &Bl[(wv * 2 + i) * 512]);
    }
    __syncthreads();
    bf16x8 a0 = *(const bf16x8*)&Al[(wv * 32 + lr) * 32 + lk];
    bf16x8 a1 = *(const bf16x8*)&Al[(wv * 32 + 16 + lr) * 32 + lk];
    for (int nj = 0; nj < 8; ++nj) {
      bf16x8 b = *(const bf16x8*)&Bl[(nj * 16 + lr) * 32 + lk];
      acc[0][nj] = __builtin_amdgcn_mfma_f32_16x16x32_bf16(a0, b, acc[0][nj], 0, 0, 0);
      acc[1][nj] = __builtin_amdgcn_mfma_f32_16x16x32_bf16(a1, b, acc[1][nj], 0, 0, 0);
    }
    __syncthreads();
  }
  const int lh = lane >> 4;
  for (int mi = 0; mi < 2; ++mi)
    for (int nj = 0; nj < 8; ++nj) {
      int col = bn * 128 + nj * 16 + lr;
      float bv = bias[col];
      for (int r = 0; r < 4; ++r) {
        int row = bm * 128 + wv * 32 + mi * 16 + lh * 4 + r;
        O[(long long)row * 512 + col] = acc[mi][nj][r] + bv;
      }
    }
}

// ---------------- LSTM: LDS-resident weights, 4-block groups, cooperative ----------------
// 64 blocks x 512 threads. bid: g = bid&15 (row-group, 128 tweet-dirs, m0=g*128), cb = bid>>4
// (64-h col slice). Whh slice 256x256 bf16 = 128 KB resident in LDS (staged once, XOR-swizzled).
// Per step: A (h_{t-1}) direct from global ping-pong, 128 MFMA/wave, xg u16x4 (4 gates contiguous),
// lane-local cell, 4-block group barrier (padded lines, acquire/release agent atomics).
__global__ __launch_bounds__(512) void k_lstm3(const u16* __restrict__ WhhP,
                                               const u16* __restrict__ XGP,
                                               u16* __restrict__ hg,      // [2][2048][256]
                                               float* __restrict__ Hf,    // [2048][256]
                                               int* __restrict__ bar) {   // [1024] ints
  extern __shared__ char lds[];  // 128 KB weights
  const int tid = threadIdx.x;
  const int w = tid >> 6, lane = tid & 63;
  const int lr = lane & 15, lh = lane >> 4;
  const int bid = blockIdx.x;
  const int g = bid & 15, cb = bid >> 4;  // group members bid = g,g+16,g+32,g+48 (same bid%8)
  const int m0 = g * 128;
  const int dir = g >> 3;
  int* cnt = bar + g * 32;        // 128-B padded
  int* gen = bar + 512 + g * 32;

  // ---- stage Whh slice once (linear dest; source pre-XOR'd by k_prep_whh) ----
  const u16* wsrc = WhhP + ((size_t)(dir * 4 + cb) << 16);
#pragma unroll
  for (int i = 0; i < 16; ++i)
    gl_lds16(wsrc + ((size_t)i * 512 + tid) * 8, lds + (i * 8 + w) * 1024);
  asm volatile("s_waitcnt vmcnt(0)" ::: "memory");
  __syncthreads();

  float cst[16] = {};
  f32x4 acc[16];
  const int mrow = m0 + w * 16;

#pragma unroll 1
  for (int t = 0; t < 64; ++t) {
    const u16* hsrc = hg + (t & 1) * (2048 * 256);
    u16* hdst = hg + ((t + 1) & 1) * (2048 * 256);
#pragma unroll
    for (int nj = 0; nj < 16; ++nj) acc[nj] = (f32x4){0.f, 0.f, 0.f, 0.f};
    // ---- h @ Whh^T : A direct from global, B from resident LDS ----
#pragma unroll
    for (int kt = 0; kt < 8; ++kt) {
      bf16x8 a = *(const bf16x8*)(hsrc + (size_t)(mrow + lr) * 256 + kt * 32 + lh * 8);
#pragma unroll
      for (int nj = 0; nj < 16; ++nj) {
        int cc = nj * 16 + lr;
        bf16x8 b = *(const bf16x8*)(lds + cc * 512 + ((kt * 64 + lh * 16) ^ ((cc & 7) << 4)));
        acc[nj] = __builtin_amdgcn_mfma_f32_16x16x32_bf16(a, b, acc[nj], 0, 0, 0);
      }
    }
    // ---- cell update: acc[g*4+s][r], gates lane-local; xg = 4 gates per u16x4 ----
#pragma unroll
    for (int rr = 0; rr < 4; ++rr) {
      int m = mrow + lh * 4 + rr;
      const u16* xb = XGP + ((size_t)(t * 2048 + m) * 4 + cb) * 256 + lr * 4;
#pragma unroll
      for (int s = 0; s < 4; ++s) {
        u16x4 xv = *(const u16x4*)(xb + s * 64);
        float gi = acc[s][rr] + bf2f(xv[0]);
        float gf = acc[4 + s][rr] + bf2f(xv[1]);
        float gg = acc[8 + s][rr] + bf2f(xv[2]);
        float go = acc[12 + s][rr] + bf2f(xv[3]);
        float cn = sigf(gf) * cst[s * 4 + rr] + sigf(gi) * tanh_(gg);
        cst[s * 4 + rr] = cn;
        float hn = sigf(go) * tanh_(cn);
        int hcol = cb * 64 + s * 16 + lr;
        if (t < 63) hdst[(size_t)m * 256 + hcol] = f2bf(hn);
        else Hf[(size_t)m * 256 + hcol] = hn;
      }
    }
    // ---- 4-block group barrier ----
    if (t < 63) {
      __threadfence();  // h stores visible agent-wide
      __syncthreads();
      if (tid == 0) {
        int prev = __hip_atomic_fetch_add(cnt, 1, __ATOMIC_ACQ_REL, __HIP_MEMORY_SCOPE_AGENT);
        if (prev == 4 * (t + 1) - 1)
          __hip_atomic_store(gen, t + 1, __ATOMIC_RELEASE, __HIP_MEMORY_SCOPE_AGENT);
        while (__hip_atomic_load(gen, __ATOMIC_ACQUIRE, __HIP_MEMORY_SCOPE_AGENT) < t + 1)
          __builtin_amdgcn_s_sleep(2);
      }
      __syncthreads();
    }
  }
}

// ---------------- attention fusion + mean over tweets ----------------
__global__ __launch_bounds__(256) void k_fusion(const float* __restrict__ Hf, const float* __restrict__ IH,
                                                const float* __restrict__ WT, const float* __restrict__ WI,
                                                float* __restrict__ msum) {
  int wv = threadIdx.x >> 6, lane = threadIdx.x & 63;
  float facc[8] = {0.f, 0.f, 0.f, 0.f, 0.f, 0.f, 0.f, 0.f};
  for (int p = 0; p < 8; ++p) {
    int n = blockIdx.x * 32 + wv * 8 + p;
    float th[8], ih[8];
    float ts = 0.f, is = 0.f;
    for (int j = 0; j < 8; ++j) {
      int e = lane * 8 + j;
      float tv = (e < 256) ? Hf[(long long)n * 256 + e] : Hf[(long long)(1024 + n) * 256 + (e - 256)];
      float iv = IH[(long long)n * 512 + e];
      th[j] = tv; ih[j] = iv;
      ts += tv * WT[e];
      is += iv * WI[e];
    }
    for (int off = 32; off > 0; off >>= 1) {
      ts += __shfl_down(ts, off);
      is += __shfl_down(is, off);
    }
    ts = __shfl(ts, 0);
    is = __shfl(is, 0);
    float a0 = 1.f / (1.f + __expf(is - ts));
    float a1 = 1.f - a0;
    for (int j = 0; j < 8; ++j) facc[j] += a0 * th[j] + a1 * ih[j];
  }
  for (int j = 0; j < 8; ++j) atomicAdd(&msum[lane * 8 + j], facc[j]);
}

// ---------------- classifier MLP ----------------
__global__ __launch_bounds__(256) void k_cls(const float* __restrict__ msum, const float* __restrict__ Wc1,
                                             const float* __restrict__ bc1, const float* __restrict__ Wc2,
                                             const float* __restrict__ bc2, float* __restrict__ out) {
  __shared__ float mf[512];
  __shared__ float hdd[512];
  __shared__ float red[2][256];
  int tid = threadIdx.x;
  for (int j = tid; j < 512; j += 256) mf[j] = msum[j] * (1.f / 1024.f);
  __syncthreads();
  for (int j = tid; j < 512; j += 256) {
    const float* wr = Wc1 + (long long)j * 512;
    float s = bc1[j];
    for (int k = 0; k < 512; ++k) s += mf[k] * wr[k];
    hdd[j] = fmaxf(s, 0.f);
  }
  __syncthreads();
  float s0 = 0.f, s1 = 0.f;
  for (int k = tid; k < 512; k += 256) {
    s0 += hdd[k] * Wc2[k];
    s1 += hdd[k] * Wc2[512 + k];
  }
  red[0][tid] = s0;
  red[1][tid] = s1;
  __syncthreads();
  if (tid < 2) {
    float s = 0.f;
    for (int k = 0; k < 256; ++k) s += red[tid][k];
    out[tid] = s + bc2[tid];
  }
}

extern "C" void kernel_launch(void* const* d_in, const int* in_sizes, int n_in,
                              void* d_out, int out_size, void* d_ws, size_t ws_size,
                              hipStream_t stream) {
  const int* tokens = (const int*)d_in[0];
  const float* images = (const float*)d_in[1];
  const float* embed = (const float*)d_in[2];
  const float* Wih_f = (const float*)d_in[3];
  const float* Whh_f = (const float*)d_in[4];
  const float* bih_f = (const float*)d_in[5];
  const float* bhh_f = (const float*)d_in[6];
  const float* Wih_b = (const float*)d_in[7];
  const float* Whh_b = (const float*)d_in[8];
  const float* bih_b = (const float*)d_in[9];
  const float* bhh_b = (const float*)d_in[10];
  const float* Wimg = (const float*)d_in[11];
  const float* bimg = (const float*)d_in[12];
  const float* W_T = (const float*)d_in[13];
  const float* W_I = (const float*)d_in[14];
  const float* Wc1 = (const float*)d_in[15];
  const float* bc1 = (const float*)d_in[16];
  const float* Wc2 = (const float*)d_in[17];
  const float* bc2 = (const float*)d_in[18];
  float* out = (float*)d_out;

  char* ws = (char*)d_ws;
  size_t off = 0;
  auto alloc = [&](size_t bytes) -> void* {
    void* p = ws + off;
    off += (bytes + 255) & ~(size_t)255;
    return p;
  };
  u16* xbf = (u16*)alloc((size_t)M1 * 512 * 2);       // 64 MiB
  u16* xgp = (u16*)alloc((size_t)M1 * 2048 * 2);      // 256 MiB (XGP layout)
  u16* wih_bf = (u16*)alloc((size_t)2048 * 512 * 2);
  u16* whhP = (u16*)alloc((size_t)2 * 262144 * 2);    // 1 MiB permuted Whh
  u16* wimg_bf = (u16*)alloc((size_t)512 * 512 * 2);
  float* bias_a = (float*)alloc((size_t)2048 * 4);
  u16* hglob = (u16*)alloc((size_t)2 * 2048 * 256 * 2);  // ping-pong h (2 MiB)
  float* hf32 = (float*)alloc((size_t)2048 * 256 * 4);
  u16* im_bf = (u16*)alloc((size_t)1024 * 512 * 2);
  float* im_h = (float*)alloc((size_t)1024 * 512 * 4);
  float* msum = (float*)alloc((size_t)512 * 4);
  int* bar = (int*)alloc((size_t)1024 * 4);

  hipMemsetAsync(hglob, 0, (size_t)2 * 2048 * 256 * 2, stream);
  hipMemsetAsync(msum, 0, (size_t)512 * 4, stream);
  hipMemsetAsync(bar, 0, (size_t)1024 * 4, stream);

  k_f2bf<<<512, 256, 0, stream>>>(Wih_f, wih_bf, 524288);
  k_f2bf<<<512, 256, 0, stream>>>(Wih_b, wih_bf + 1024 * 512, 524288);
  k_f2bf<<<256, 256, 0, stream>>>(Wimg, wimg_bf, 262144);
  k_prep_whh<<<2048, 256, 0, stream>>>(Whh_f, Whh_b, whhP);
  k_bias<<<8, 256, 0, stream>>>(bih_f, bhh_f, bih_b, bhh_b, bias_a);

  k_gather<<<16384, 256, 0, stream>>>(tokens, embed, xbf);
  k_gemm_xg<<<8192, 256, 0, stream>>>(xbf, wih_bf, bias_a, xgp);

  k_imgmean<<<1024, 256, 0, stream>>>(images, im_bf);
  k_gemm_img<<<dim3(8, 4), 256, 0, stream>>>(im_bf, wimg_bf, bimg, im_h);

  hipFuncSetAttribute((const void*)k_lstm3, hipFuncAttributeMaxDynamicSharedMemorySize, 131072);
  {
    void* args[] = {(void*)&whhP, (void*)&xgp, (void*)&hglob, (void*)&hf32, (void*)&bar};
    hipLaunchCooperativeKernel((const void*)k_lstm3, dim3(64), dim3(512), args, 131072, stream);
  }

  k_fusion<<<32, 256, 0, stream>>>(hf32, im_h, W_T, W_I, msum);
  k_cls<<<1, 256, 0, stream>>>(msum, Wc1, bc1, Wc2, bc2, out);
}

// Round 6
// 878.896 us; speedup vs baseline: 2.6001x; 2.6001x over previous
//
#include <hip/hip_runtime.h>

typedef unsigned short u16;
typedef unsigned int u32;
typedef __bf16 bf16x8 __attribute__((ext_vector_type(8)));
typedef float f32x4 __attribute__((ext_vector_type(4)));
typedef u16 u16x4 __attribute__((ext_vector_type(4)));
typedef u16 u16x8 __attribute__((ext_vector_type(8)));

#define N_TW 1024
#define L_TOK 64
#define M1 (N_TW * L_TOK)

__device__ __forceinline__ u16 f2bf(float f) {
  u32 u = __builtin_bit_cast(u32, f);
  u += 0x7fffu + ((u >> 16) & 1u);
  return (u16)(u >> 16);
}
__device__ __forceinline__ float bf2f(u16 b) {
  u32 u = ((u32)b) << 16;
  return __builtin_bit_cast(float, u);
}
__device__ __forceinline__ void gl_lds16(const void* g, void* l) {
  __builtin_amdgcn_global_load_lds((const __attribute__((address_space(1))) u32*)g,
                                   (__attribute__((address_space(3))) u32*)l, 16, 0, 0);
}
__device__ __forceinline__ float sigf(float x) { return 1.f / (1.f + __expf(-x)); }
__device__ __forceinline__ float tanh_(float x) { return 1.f - 2.f / (__expf(2.f * x) + 1.f); }

// ---------------- prep: fp32 -> bf16 weight conversion ----------------
__global__ __launch_bounds__(256) void k_f2bf(const float* __restrict__ s, u16* __restrict__ d, int n) {
  int i = (blockIdx.x * 256 + threadIdx.x) * 4;
  if (i < n) {
    float4 v = *(const float4*)(s + i);
    u16x4 o;
    o.x = f2bf(v.x); o.y = f2bf(v.y); o.z = f2bf(v.z); o.w = f2bf(v.w);
    *(u16x4*)(d + i) = o;
  }
}

__global__ __launch_bounds__(256) void k_bias(const float* __restrict__ a, const float* __restrict__ b,
                                              const float* __restrict__ c, const float* __restrict__ d,
                                              float* __restrict__ o) {
  int i = blockIdx.x * 256 + threadIdx.x;  // 0..2047
  o[i] = (i < 1024) ? (a[i] + b[i]) : (c[i - 1024] + d[i - 1024]);
}

// ---------------- Whh pack into MFMA fragment order ----------------
// WP[dir][w(8)][s(8)][j(8)][l(64)][i(8)] : fragment for (wave w, col-tile j, k-slab s):
// lane l holds B[gate=j>>1][h=w*32+(j&1)*16+(l&15)][k=s*32+(l>>4)*8+i].
__global__ __launch_bounds__(256) void k_prep_wp(const float* __restrict__ Wf, const float* __restrict__ Wb,
                                                 u16* __restrict__ P) {
  int e = blockIdx.x * 256 + threadIdx.x;  // 0..524287
  int i = e & 7, l = (e >> 3) & 63, j = (e >> 9) & 7, s = (e >> 12) & 7, w = (e >> 15) & 7, dir = e >> 18;
  int g = j >> 1, h = w * 32 + ((j & 1) << 4) + (l & 15), k = s * 32 + ((l >> 4) << 3) + i;
  const float* W = dir ? Wb : Wf;
  P[e] = f2bf(W[(g * 256 + h) * 256 + k]);
}

// ---------------- embedding gather + bf16 convert ----------------
__global__ __launch_bounds__(256) void k_gather(const int* __restrict__ tok, const float* __restrict__ emb,
                                                u16* __restrict__ x) {
  long long t = (long long)blockIdx.x * 256 + threadIdx.x;
  long long base = t * 8;
  int row = (int)(base >> 9);
  int col = (int)(base & 511);
  long long src = (long long)tok[row] * 512 + col;
  float4 a = *(const float4*)(emb + src);
  float4 b = *(const float4*)(emb + src + 4);
  u16x8 o;
  o[0] = f2bf(a.x); o[1] = f2bf(a.y); o[2] = f2bf(a.z); o[3] = f2bf(a.w);
  o[4] = f2bf(b.x); o[5] = f2bf(b.y); o[6] = f2bf(b.z); o[7] = f2bf(b.w);
  *(u16x8*)(x + base) = o;
}

// ---------------- GEMM: xg = X @ Wih^T + bias, written in XGP layout ----------------
// XGP[t][m(2048)][h(256)][g(4)] (4 gates contiguous per (m,h)); slot t = dir ? 63-l : l, m = dir*1024+n.
__global__ __launch_bounds__(256) void k_gemm_xg(const u16* __restrict__ X, const u16* __restrict__ W,
                                                 const float* __restrict__ bias, u16* __restrict__ XGP) {
  __shared__ u16 Al[128 * 64];
  __shared__ u16 Bl[128 * 64];
  const int tid = threadIdx.x;
  const int wv = tid >> 6, lane = tid & 63;
  const int lr = lane & 15, lh = lane >> 4;
  const int bid = blockIdx.x;
  const int local = bid >> 3;
  const int bn = local & 15;
  const int bm = (bid & 7) * 64 + (local >> 4);
  f32x4 acc[2][8] = {};
  for (int kt = 0; kt < 8; ++kt) {
#pragma unroll
    for (int r = 0; r < 4; ++r) {
      int chunk = r * 4 + wv;
      int s = chunk * 1024 + lane * 16;
      int row = s >> 7;
      int kb = (s & 127) ^ ((row & 7) << 4);
      gl_lds16(X + (size_t)(bm * 128 + row) * 512 + kt * 64 + (kb >> 1), (char*)Al + chunk * 1024);
      gl_lds16(W + (size_t)(bn * 128 + row) * 512 + kt * 64 + (kb >> 1), (char*)Bl + chunk * 1024);
    }
    __syncthreads();
#pragma unroll
    for (int ks = 0; ks < 2; ++ks) {
      int kbf = ks * 64 + lh * 16;
      int ra = wv * 32 + lr;
      int xa = kbf ^ ((ra & 7) << 4);
      bf16x8 a0 = *(const bf16x8*)((const char*)Al + ra * 128 + xa);
      bf16x8 a1 = *(const bf16x8*)((const char*)Al + (ra + 16) * 128 + xa);
#pragma unroll
      for (int nj = 0; nj < 8; ++nj) {
        int c = nj * 16 + lr;
        bf16x8 b = *(const bf16x8*)((const char*)Bl + c * 128 + (kbf ^ ((c & 7) << 4)));
        acc[0][nj] = __builtin_amdgcn_mfma_f32_16x16x32_bf16(a0, b, acc[0][nj], 0, 0, 0);
        acc[1][nj] = __builtin_amdgcn_mfma_f32_16x16x32_bf16(a1, b, acc[1][nj], 0, 0, 0);
      }
    }
    __syncthreads();
  }
#pragma unroll
  for (int mi = 0; mi < 2; ++mi)
#pragma unroll
    for (int nj = 0; nj < 8; ++nj) {
      int col = bn * 128 + nj * 16 + lr;
      float bv = bias[col];
      int dirg = col >> 10, gg = (col >> 8) & 3, h = col & 255;
#pragma unroll
      for (int r = 0; r < 4; ++r) {
        int row = bm * 128 + wv * 32 + mi * 16 + lh * 4 + r;
        int n = row >> 6, l = row & 63;
        int tt = dirg ? (63 - l) : l;
        int m = dirg * 1024 + n;
        size_t idx = ((size_t)(tt * 2048 + m) * 256 + h) * 4 + gg;
        XGP[idx] = f2bf(acc[mi][nj][r] + bv);
      }
    }
}

// ---------------- image mean over 49 positions ----------------
__global__ __launch_bounds__(256) void k_imgmean(const float* __restrict__ img, u16* __restrict__ o) {
  int n = blockIdx.x;
  for (int j = 0; j < 2; ++j) {
    int col = threadIdx.x + j * 256;
    const float* p = img + (long long)n * 49 * 512 + col;
    float s = 0.f;
    for (int r = 0; r < 49; ++r) s += p[r * 512];
    o[(long long)n * 512 + col] = f2bf(s * (1.f / 49.f));
  }
}

// ---------------- image GEMM ----------------
__global__ __launch_bounds__(256) void k_gemm_img(const u16* __restrict__ A, const u16* __restrict__ W,
                                                  const float* __restrict__ bias, float* __restrict__ O) {
  __shared__ u16 Al[128 * 32];
  __shared__ u16 Bl[128 * 32];
  const int tid = threadIdx.x;
  const int wv = tid >> 6, lane = tid & 63;
  const int bm = blockIdx.x, bn = blockIdx.y;
  f32x4 acc[2][8] = {};
  const int lr = lane & 15, lk = (lane >> 4) * 8;
  for (int kt = 0; kt < 16; ++kt) {
    for (int i = 0; i < 2; ++i) {
      int lin = (wv * 2 + i) * 64 + lane;
      int r = lin >> 2, kc = lin & 3;
      int k = kt * 32 + kc * 8;
      gl_lds16(A + (long long)(bm * 128 + r) * 512 + k, &Al[(wv * 2 + i) * 512]);
      gl_lds16(W + (long long)(bn * 128 + r) * 512 + k, &Bl[(wv * 2 + i) * 512]);
    }
    __syncthreads();
    bf16x8 a0 = *(const bf16x8*)&Al[(wv * 32 + lr) * 32 + lk];
    bf16x8 a1 = *(const bf16x8*)&Al[(wv * 32 + 16 + lr) * 32 + lk];
    for (int nj = 0; nj < 8; ++nj) {
      bf16x8 b = *(const bf16x8*)&Bl[(nj * 16 + lr) * 32 + lk];
      acc[0][nj] = __builtin_amdgcn_mfma_f32_16x16x32_bf16(a0, b, acc[0][nj], 0, 0, 0);
      acc[1][nj] = __builtin_amdgcn_mfma_f32_16x16x32_bf16(a1, b, acc[1][nj], 0, 0, 0);
    }
    __syncthreads();
  }
  const int lh = lane >> 4;
  for (int mi = 0; mi < 2; ++mi)
    for (int nj = 0; nj < 8; ++nj) {
      int col = bn * 128 + nj * 16 + lr;
      float bv = bias[col];
      for (int r = 0; r < 4; ++r) {
        int row = bm * 128 + wv * 32 + mi * 16 + lh * 4 + r;
        O[(long long)row * 512 + col] = acc[mi][nj][r] + bv;
      }
    }
}

// ---------------- LSTM: weights resident in VGPR(4 slabs)+LDS(2)+L2-stream(2), block-local ----------------
// 128 blocks x 512 thr (8 waves), plain launch, ZERO inter-block deps. Block: dir=b>>6, 16 tweets.
// Wave w: h-slice [w*32,w*32+32), cols gate-major (g*32+h) -> acc[j],acc[j+2],acc[j+4],acc[j+6]
// give i,f,g,o for the same h in the same lane. h ping-pong in LDS (XOR-swizzled), c in registers.
// LDS: [0,128K) B slabs 4,5 per-wave packed; [128K,144K) h[2][16][256].
__global__ __launch_bounds__(512, 2) void k_lstm4(const u16* __restrict__ WP,
                                                  const u16* __restrict__ XGP,
                                                  float* __restrict__ Hf) {
  extern __shared__ char lds[];
  const int tid = threadIdx.x;
  const int w = tid >> 6, l = tid & 63;
  const int l15 = l & 15, l4 = l >> 4;
  const int b = blockIdx.x;
  const int dir = b >> 6;
  const int m0 = (b & 63) * 16;
  const size_t WB = ((size_t)dir * 8 + w) * 8;

  // ---- reg-resident slabs 0..3 (32 fragments = 128 VGPR) ----
  bf16x8 breg[4][8];
#pragma unroll
  for (int s = 0; s < 4; ++s)
#pragma unroll
    for (int j = 0; j < 8; ++j)
      breg[s][j] = *(const bf16x8*)(WP + (((WB + s) * 8 + j) << 9) + l * 8);

  // ---- stage LDS slabs 4,5 (16 KB per wave, linear) ----
  const u16* wsrc = WP + (((WB + 4) * 8) << 9);
#pragma unroll
  for (int r = 0; r < 16; ++r)
    gl_lds16(wsrc + r * 512 + l * 8, lds + w * 16384 + r * 1024);

  // ---- zero h buffer 0 ----
  u32* hz = (u32*)(lds + 131072);
  hz[tid * 4 + 0] = 0; hz[tid * 4 + 1] = 0; hz[tid * 4 + 2] = 0; hz[tid * 4 + 3] = 0;
  __syncthreads();

  float cst[8] = {};
#pragma unroll 1
  for (int t = 0; t < 64; ++t) {
    const char* hrd = lds + 131072 + (t & 1) * 8192;
    char* hwr = lds + 131072 + ((t + 1) & 1) * 8192;
    const u16* xgt = XGP + ((size_t)t * 2048 + dir * 1024 + m0) * 1024;
    // issue stream slab 6 + xg loads early (hide L2 latency under MFMA)
    bf16x8 bs[8];
#pragma unroll
    for (int j = 0; j < 8; ++j)
      bs[j] = *(const bf16x8*)(WP + (((WB + 6) * 8 + j) << 9) + l * 8);
    u16x4 xv[2][4];
#pragma unroll
    for (int hb = 0; hb < 2; ++hb)
#pragma unroll
      for (int r = 0; r < 4; ++r)
        xv[hb][r] = *(const u16x4*)(xgt + (l4 * 4 + r) * 1024 + (w * 32 + hb * 16 + l15) * 4);
    f32x4 acc[8];
#pragma unroll
    for (int j = 0; j < 8; ++j) acc[j] = (f32x4){0.f, 0.f, 0.f, 0.f};
    // reg slabs 0..3
#pragma unroll
    for (int s = 0; s < 4; ++s) {
      bf16x8 a = *(const bf16x8*)(hrd + l15 * 512 + ((s * 64 + l4 * 16) ^ ((l15 & 7) << 4)));
#pragma unroll
      for (int j = 0; j < 8; ++j)
        acc[j] = __builtin_amdgcn_mfma_f32_16x16x32_bf16(a, breg[s][j], acc[j], 0, 0, 0);
    }
    // LDS slabs 4,5
#pragma unroll
    for (int sp = 0; sp < 2; ++sp) {
      bf16x8 a = *(const bf16x8*)(hrd + l15 * 512 + (((4 + sp) * 64 + l4 * 16) ^ ((l15 & 7) << 4)));
#pragma unroll
      for (int j = 0; j < 8; ++j) {
        bf16x8 bb = *(const bf16x8*)(lds + w * 16384 + (sp * 8 + j) * 1024 + l * 16);
        acc[j] = __builtin_amdgcn_mfma_f32_16x16x32_bf16(a, bb, acc[j], 0, 0, 0);
      }
    }
    // stream slab 6 use
    {
      bf16x8 a = *(const bf16x8*)(hrd + l15 * 512 + ((6 * 64 + l4 * 16) ^ ((l15 & 7) << 4)));
#pragma unroll
      for (int j = 0; j < 8; ++j)
        acc[j] = __builtin_amdgcn_mfma_f32_16x16x32_bf16(a, bs[j], acc[j], 0, 0, 0);
    }
    __builtin_amdgcn_sched_barrier(0);  // keep slab-7 loads below slab-6 MFMAs (reg reuse, no hoist)
    // stream slab 7
#pragma unroll
    for (int j = 0; j < 8; ++j)
      bs[j] = *(const bf16x8*)(WP + (((WB + 7) * 8 + j) << 9) + l * 8);
    {
      bf16x8 a = *(const bf16x8*)(hrd + l15 * 512 + ((7 * 64 + l4 * 16) ^ ((l15 & 7) << 4)));
#pragma unroll
      for (int j = 0; j < 8; ++j)
        acc[j] = __builtin_amdgcn_mfma_f32_16x16x32_bf16(a, bs[j], acc[j], 0, 0, 0);
    }
    // ---- cell update (lane-local) ----
#pragma unroll
    for (int hb = 0; hb < 2; ++hb)
#pragma unroll
      for (int r = 0; r < 4; ++r) {
        float gi = acc[0 + hb][r] + bf2f(xv[hb][r][0]);
        float gf = acc[2 + hb][r] + bf2f(xv[hb][r][1]);
        float gg = acc[4 + hb][r] + bf2f(xv[hb][r][2]);
        float go = acc[6 + hb][r] + bf2f(xv[hb][r][3]);
        float cn = sigf(gf) * cst[hb * 4 + r] + sigf(gi) * tanh_(gg);
        cst[hb * 4 + r] = cn;
        float hn = sigf(go) * tanh_(cn);
        int row = l4 * 4 + r;
        int hcol = w * 32 + hb * 16 + l15;
        if (t < 63)
          *(u16*)(hwr + row * 512 + ((2 * hcol) ^ ((row & 7) << 4))) = f2bf(hn);
        else
          Hf[(size_t)(dir * 1024 + m0 + row) * 256 + hcol] = hn;
      }
    __syncthreads();
  }
}

// ---------------- attention fusion + mean over tweets ----------------
__global__ __launch_bounds__(256) void k_fusion(const float* __restrict__ Hf, const float* __restrict__ IH,
                                                const float* __restrict__ WT, const float* __restrict__ WI,
                                                float* __restrict__ msum) {
  int wv = threadIdx.x >> 6, lane = threadIdx.x & 63;
  float facc[8] = {0.f, 0.f, 0.f, 0.f, 0.f, 0.f, 0.f, 0.f};
  for (int p = 0; p < 8; ++p) {
    int n = blockIdx.x * 32 + wv * 8 + p;
    float th[8], ih[8];
    float ts = 0.f, is = 0.f;
    for (int j = 0; j < 8; ++j) {
      int e = lane * 8 + j;
      float tv = (e < 256) ? Hf[(long long)n * 256 + e] : Hf[(long long)(1024 + n) * 256 + (e - 256)];
      float iv = IH[(long long)n * 512 + e];
      th[j] = tv; ih[j] = iv;
      ts += tv * WT[e];
      is += iv * WI[e];
    }
    for (int off = 32; off > 0; off >>= 1) {
      ts += __shfl_down(ts, off);
      is += __shfl_down(is, off);
    }
    ts = __shfl(ts, 0);
    is = __shfl(is, 0);
    float a0 = 1.f / (1.f + __expf(is - ts));
    float a1 = 1.f - a0;
    for (int j = 0; j < 8; ++j) facc[j] += a0 * th[j] + a1 * ih[j];
  }
  for (int j = 0; j < 8; ++j) atomicAdd(&msum[lane * 8 + j], facc[j]);
}

// ---------------- classifier MLP ----------------
__global__ __launch_bounds__(256) void k_cls(const float* __restrict__ msum, const float* __restrict__ Wc1,
                                             const float* __restrict__ bc1, const float* __restrict__ Wc2,
                                             const float* __restrict__ bc2, float* __restrict__ out) {
  __shared__ float mf[512];
  __shared__ float hdd[512];
  __shared__ float red[2][256];
  int tid = threadIdx.x;
  for (int j = tid; j < 512; j += 256) mf[j] = msum[j] * (1.f / 1024.f);
  __syncthreads();
  for (int j = tid; j < 512; j += 256) {
    const float* wr = Wc1 + (long long)j * 512;
    float s = bc1[j];
    for (int k = 0; k < 512; ++k) s += mf[k] * wr[k];
    hdd[j] = fmaxf(s, 0.f);
  }
  __syncthreads();
  float s0 = 0.f, s1 = 0.f;
  for (int k = tid; k < 512; k += 256) {
    s0 += hdd[k] * Wc2[k];
    s1 += hdd[k] * Wc2[512 + k];
  }
  red[0][tid] = s0;
  red[1][tid] = s1;
  __syncthreads();
  if (tid < 2) {
    float s = 0.f;
    for (int k = 0; k < 256; ++k) s += red[tid][k];
    out[tid] = s + bc2[tid];
  }
}

extern "C" void kernel_launch(void* const* d_in, const int* in_sizes, int n_in,
                              void* d_out, int out_size, void* d_ws, size_t ws_size,
                              hipStream_t stream) {
  const int* tokens = (const int*)d_in[0];
  const float* images = (const float*)d_in[1];
  const float* embed = (const float*)d_in[2];
  const float* Wih_f = (const float*)d_in[3];
  const float* Whh_f = (const float*)d_in[4];
  const float* bih_f = (const float*)d_in[5];
  const float* bhh_f = (const float*)d_in[6];
  const float* Wih_b = (const float*)d_in[7];
  const float* Whh_b = (const float*)d_in[8];
  const float* bih_b = (const float*)d_in[9];
  const float* bhh_b = (const float*)d_in[10];
  const float* Wimg = (const float*)d_in[11];
  const float* bimg = (const float*)d_in[12];
  const float* W_T = (const float*)d_in[13];
  const float* W_I = (const float*)d_in[14];
  const float* Wc1 = (const float*)d_in[15];
  const float* bc1 = (const float*)d_in[16];
  const float* Wc2 = (const float*)d_in[17];
  const float* bc2 = (const float*)d_in[18];
  float* out = (float*)d_out;

  char* ws = (char*)d_ws;
  size_t off = 0;
  auto alloc = [&](size_t bytes) -> void* {
    void* p = ws + off;
    off += (bytes + 255) & ~(size_t)255;
    return p;
  };
  u16* xbf = (u16*)alloc((size_t)M1 * 512 * 2);       // 64 MiB
  u16* xgp = (u16*)alloc((size_t)M1 * 2048 * 2);      // 256 MiB (XGP layout)
  u16* wih_bf = (u16*)alloc((size_t)2048 * 512 * 2);
  u16* wp = (u16*)alloc((size_t)2 * 262144 * 2);      // 1 MiB fragment-packed Whh
  u16* wimg_bf = (u16*)alloc((size_t)512 * 512 * 2);
  float* bias_a = (float*)alloc((size_t)2048 * 4);
  float* hf32 = (float*)alloc((size_t)2048 * 256 * 4);
  u16* im_bf = (u16*)alloc((size_t)1024 * 512 * 2);
  float* im_h = (float*)alloc((size_t)1024 * 512 * 4);
  float* msum = (float*)alloc((size_t)512 * 4);

  hipMemsetAsync(msum, 0, (size_t)512 * 4, stream);

  k_f2bf<<<512, 256, 0, stream>>>(Wih_f, wih_bf, 524288);
  k_f2bf<<<512, 256, 0, stream>>>(Wih_b, wih_bf + 1024 * 512, 524288);
  k_f2bf<<<256, 256, 0, stream>>>(Wimg, wimg_bf, 262144);
  k_prep_wp<<<2048, 256, 0, stream>>>(Whh_f, Whh_b, wp);
  k_bias<<<8, 256, 0, stream>>>(bih_f, bhh_f, bih_b, bhh_b, bias_a);

  k_gather<<<16384, 256, 0, stream>>>(tokens, embed, xbf);
  k_gemm_xg<<<8192, 256, 0, stream>>>(xbf, wih_bf, bias_a, xgp);

  k_imgmean<<<1024, 256, 0, stream>>>(images, im_bf);
  k_gemm_img<<<dim3(8, 4), 256, 0, stream>>>(im_bf, wimg_bf, bimg, im_h);

  hipFuncSetAttribute((const void*)k_lstm4, hipFuncAttributeMaxDynamicSharedMemorySize, 147456);
  k_lstm4<<<128, 512, 147456, stream>>>(wp, xgp, hf32);

  k_fusion<<<32, 256, 0, stream>>>(hf32, im_h, W_T, W_I, msum);
  k_cls<<<1, 256, 0, stream>>>(msum, Wc1, bc1, Wc2, bc2, out);
}

// Round 7
// 856.363 us; speedup vs baseline: 2.6685x; 1.0263x over previous
//
#include <hip/hip_runtime.h>

typedef unsigned short u16;
typedef unsigned int u32;
typedef __bf16 bf16x8 __attribute__((ext_vector_type(8)));
typedef float f32x4 __attribute__((ext_vector_type(4)));
typedef u16 u16x4 __attribute__((ext_vector_type(4)));
typedef u16 u16x8 __attribute__((ext_vector_type(8)));
typedef int i32x4 __attribute__((ext_vector_type(4)));

#define N_TW 1024
#define L_TOK 64
#define M1 (N_TW * L_TOK)

__device__ __forceinline__ u16 f2bf(float f) {
  u32 u = __builtin_bit_cast(u32, f);
  u += 0x7fffu + ((u >> 16) & 1u);
  return (u16)(u >> 16);
}
__device__ __forceinline__ float bf2f(u16 b) {
  u32 u = ((u32)b) << 16;
  return __builtin_bit_cast(float, u);
}
__device__ __forceinline__ void gl_lds16(const void* g, void* l) {
  __builtin_amdgcn_global_load_lds((const __attribute__((address_space(1))) u32*)g,
                                   (__attribute__((address_space(3))) u32*)l, 16, 0, 0);
}
__device__ __forceinline__ float sigf(float x) { return 1.f / (1.f + __expf(-x)); }
__device__ __forceinline__ float tanh_(float x) { return 1.f - 2.f / (__expf(2.f * x) + 1.f); }

// ---------------- prep: fp32 -> bf16 weight conversion ----------------
__global__ __launch_bounds__(256) void k_f2bf(const float* __restrict__ s, u16* __restrict__ d, int n) {
  int i = (blockIdx.x * 256 + threadIdx.x) * 4;
  if (i < n) {
    float4 v = *(const float4*)(s + i);
    u16x4 o;
    o.x = f2bf(v.x); o.y = f2bf(v.y); o.z = f2bf(v.z); o.w = f2bf(v.w);
    *(u16x4*)(d + i) = o;
  }
}

__global__ __launch_bounds__(256) void k_bias(const float* __restrict__ a, const float* __restrict__ b,
                                              const float* __restrict__ c, const float* __restrict__ d,
                                              float* __restrict__ o) {
  int i = blockIdx.x * 256 + threadIdx.x;  // 0..2047
  o[i] = (i < 1024) ? (a[i] + b[i]) : (c[i - 1024] + d[i - 1024]);
}

// ---------------- Whh pack into per-(wave16) MFMA fragment order ----------------
// WP2[dir][w(16)][s(8)][g(4)][l(64)][i(8)]: lane l of fragment (w,s,g) holds
// B[gate=g][h = w*16 + (l&15)][k = s*32 + (l>>4)*8 + i].
__global__ __launch_bounds__(256) void k_prep_wp2(const float* __restrict__ Wf, const float* __restrict__ Wb,
                                                  u16* __restrict__ P) {
  int e = blockIdx.x * 256 + threadIdx.x;  // 0..524287
  int i = e & 7, l = (e >> 3) & 63, g = (e >> 9) & 3, s = (e >> 11) & 7, w = (e >> 14) & 15, dir = e >> 18;
  int h = w * 16 + (l & 15), k = s * 32 + ((l >> 4) << 3) + i;
  const float* W = dir ? Wb : Wf;
  P[e] = f2bf(W[(g * 256 + h) * 256 + k]);
}

// ---------------- embedding gather + bf16 convert ----------------
__global__ __launch_bounds__(256) void k_gather(const int* __restrict__ tok, const float* __restrict__ emb,
                                                u16* __restrict__ x) {
  long long t = (long long)blockIdx.x * 256 + threadIdx.x;
  long long base = t * 8;
  int row = (int)(base >> 9);
  int col = (int)(base & 511);
  long long src = (long long)tok[row] * 512 + col;
  float4 a = *(const float4*)(emb + src);
  float4 b = *(const float4*)(emb + src + 4);
  u16x8 o;
  o[0] = f2bf(a.x); o[1] = f2bf(a.y); o[2] = f2bf(a.z); o[3] = f2bf(a.w);
  o[4] = f2bf(b.x); o[5] = f2bf(b.y); o[6] = f2bf(b.z); o[7] = f2bf(b.w);
  *(u16x8*)(x + base) = o;
}

// ---------------- GEMM: xg = X @ Wih^T + bias, written in XGP layout ----------------
// XGP[t][m(2048)][h(256)][g(4)] (4 gates contiguous per (m,h)); slot t = dir ? 63-l : l, m = dir*1024+n.
__global__ __launch_bounds__(256) void k_gemm_xg(const u16* __restrict__ X, const u16* __restrict__ W,
                                                 const float* __restrict__ bias, u16* __restrict__ XGP) {
  __shared__ u16 Al[128 * 64];
  __shared__ u16 Bl[128 * 64];
  const int tid = threadIdx.x;
  const int wv = tid >> 6, lane = tid & 63;
  const int lr = lane & 15, lh = lane >> 4;
  const int bid = blockIdx.x;
  const int local = bid >> 3;
  const int bn = local & 15;
  const int bm = (bid & 7) * 64 + (local >> 4);
  f32x4 acc[2][8] = {};
  for (int kt = 0; kt < 8; ++kt) {
#pragma unroll
    for (int r = 0; r < 4; ++r) {
      int chunk = r * 4 + wv;
      int s = chunk * 1024 + lane * 16;
      int row = s >> 7;
      int kb = (s & 127) ^ ((row & 7) << 4);
      gl_lds16(X + (size_t)(bm * 128 + row) * 512 + kt * 64 + (kb >> 1), (char*)Al + chunk * 1024);
      gl_lds16(W + (size_t)(bn * 128 + row) * 512 + kt * 64 + (kb >> 1), (char*)Bl + chunk * 1024);
    }
    __syncthreads();
#pragma unroll
    for (int ks = 0; ks < 2; ++ks) {
      int kbf = ks * 64 + lh * 16;
      int ra = wv * 32 + lr;
      int xa = kbf ^ ((ra & 7) << 4);
      bf16x8 a0 = *(const bf16x8*)((const char*)Al + ra * 128 + xa);
      bf16x8 a1 = *(const bf16x8*)((const char*)Al + (ra + 16) * 128 + xa);
#pragma unroll
      for (int nj = 0; nj < 8; ++nj) {
        int c = nj * 16 + lr;
        bf16x8 b = *(const bf16x8*)((const char*)Bl + c * 128 + (kbf ^ ((c & 7) << 4)));
        acc[0][nj] = __builtin_amdgcn_mfma_f32_16x16x32_bf16(a0, b, acc[0][nj], 0, 0, 0);
        acc[1][nj] = __builtin_amdgcn_mfma_f32_16x16x32_bf16(a1, b, acc[1][nj], 0, 0, 0);
      }
    }
    __syncthreads();
  }
#pragma unroll
  for (int mi = 0; mi < 2; ++mi)
#pragma unroll
    for (int nj = 0; nj < 8; ++nj) {
      int col = bn * 128 + nj * 16 + lr;
      float bv = bias[col];
      int dirg = col >> 10, gg = (col >> 8) & 3, h = col & 255;
#pragma unroll
      for (int r = 0; r < 4; ++r) {
        int row = bm * 128 + wv * 32 + mi * 16 + lh * 4 + r;
        int n = row >> 6, l = row & 63;
        int tt = dirg ? (63 - l) : l;
        int m = dirg * 1024 + n;
        size_t idx = ((size_t)(tt * 2048 + m) * 256 + h) * 4 + gg;
        XGP[idx] = f2bf(acc[mi][nj][r] + bv);
      }
    }
}

// ---------------- image mean over 49 positions ----------------
__global__ __launch_bounds__(256) void k_imgmean(const float* __restrict__ img, u16* __restrict__ o) {
  int n = blockIdx.x;
  for (int j = 0; j < 2; ++j) {
    int col = threadIdx.x + j * 256;
    const float* p = img + (long long)n * 49 * 512 + col;
    float s = 0.f;
    for (int r = 0; r < 49; ++r) s += p[r * 512];
    o[(long long)n * 512 + col] = f2bf(s * (1.f / 49.f));
  }
}

// ---------------- image GEMM ----------------
__global__ __launch_bounds__(256) void k_gemm_img(const u16* __restrict__ A, const u16* __restrict__ W,
                                                  const float* __restrict__ bias, float* __restrict__ O) {
  __shared__ u16 Al[128 * 32];
  __shared__ u16 Bl[128 * 32];
  const int tid = threadIdx.x;
  const int wv = tid >> 6, lane = tid & 63;
  const int bm = blockIdx.x, bn = blockIdx.y;
  f32x4 acc[2][8] = {};
  const int lr = lane & 15, lk = (lane >> 4) * 8;
  for (int kt = 0; kt < 16; ++kt) {
    for (int i = 0; i < 2; ++i) {
      int lin = (wv * 2 + i) * 64 + lane;
      int r = lin >> 2, kc = lin & 3;
      int k = kt * 32 + kc * 8;
      gl_lds16(A + (long long)(bm * 128 + r) * 512 + k, &Al[(wv * 2 + i) * 512]);
      gl_lds16(W + (long long)(bn * 128 + r) * 512 + k, &Bl[(wv * 2 + i) * 512]);
    }
    __syncthreads();
    bf16x8 a0 = *(const bf16x8*)&Al[(wv * 32 + lr) * 32 + lk];
    bf16x8 a1 = *(const bf16x8*)&Al[(wv * 32 + 16 + lr) * 32 + lk];
    for (int nj = 0; nj < 8; ++nj) {
      bf16x8 b = *(const bf16x8*)&Bl[(nj * 16 + lr) * 32 + lk];
      acc[0][nj] = __builtin_amdgcn_mfma_f32_16x16x32_bf16(a0, b, acc[0][nj], 0, 0, 0);
      acc[1][nj] = __builtin_amdgcn_mfma_f32_16x16x32_bf16(a1, b, acc[1][nj], 0, 0, 0);
    }
    __syncthreads();
  }
  const int lh = lane >> 4;
  for (int mi = 0; mi < 2; ++mi)
    for (int nj = 0; nj < 8; ++nj) {
      int col = bn * 128 + nj * 16 + lr;
      float bv = bias[col];
      for (int r = 0; r < 4; ++r) {
        int row = bm * 128 + wv * 32 + mi * 16 + lh * 4 + r;
        O[(long long)row * 512 + col] = acc[mi][nj][r] + bv;
      }
    }
}

// ---------------- LSTM: 16 waves/block (4/SIMD), weights reg(2)+LDS(2)+stream(4) ----------------
// 128 blocks x 1024 thr, plain launch, zero inter-block deps. Block: dir=b>>6, 16 tweets m0=(b&63)*16.
// Wave w owns h-slice [w*16, w*16+16) x 4 gates -> 4 col-frags; acc[g][r] gives gate g for
// h = w*16+l15, row = l4*4+r -> cell fully lane-local, 4 cells/lane. h ping-pong in LDS (XOR-swz).
// LDS: [0,128K) slabs 2,3 (128 frags x 1KB); [128K,144K) h[2][16][256] bf16.
__global__ __launch_bounds__(1024) void k_lstm5(const u16* __restrict__ WP2,
                                                const u16* __restrict__ XGP,
                                                float* __restrict__ Hf) {
  extern __shared__ char lds[];
  const int tid = threadIdx.x;
  const int w = tid >> 6, l = tid & 63;
  const int l15 = l & 15, l4 = l >> 4;
  const int b = blockIdx.x;
  const int dir = b >> 6;
  const int m0 = (b & 63) * 16;
  const u16* wbase = WP2 + (((size_t)dir * 16 + w) * 8) * 2048;  // this wave's 8 slabs x 4 frags

  // ---- stage LDS slabs 2,3 once: 128 frags x 1 KB ----
#pragma unroll
  for (int i = 0; i < 8; ++i) {
    int chunk = i * 1024 + tid;
    int f = chunk >> 6;       // f = wR*8 + sl*4 + g
    int lane = chunk & 63;
    int wR = f >> 3, sl = (f >> 2) & 1, g = f & 3;
    const u16* src = WP2 + ((((size_t)dir * 16 + wR) * 8 + (2 + sl)) * 4 + g) * 512 + lane * 8;
    gl_lds16(src, lds + f * 1024 + lane * 16);
  }
  // ---- reg slabs 0,1 (8 frags = 32 VGPR) ----
  bf16x8 breg[2][4];
#pragma unroll
  for (int s = 0; s < 2; ++s)
#pragma unroll
    for (int g = 0; g < 4; ++g)
      breg[s][g] = *(const bf16x8*)(wbase + ((s * 4 + g) * 64 + l) * 8);
  // ---- zero both h buffers (16 KB) ----
  *(i32x4*)(lds + 131072 + tid * 16) = (i32x4){0, 0, 0, 0};
  __syncthreads();  // also drains gl_lds (compiler emits vmcnt(0) before barrier)

  float cst[4] = {};
#pragma unroll 1
  for (int t = 0; t < 64; ++t) {
    const char* hrd = lds + 131072 + (t & 1) * 8192;
    char* hwr = lds + 131072 + ((t + 1) & 1) * 8192;
    const u16* xgt = XGP + ((size_t)t * 2048 + dir * 1024 + m0) * 1024;
    u16x4 xv[4];
#pragma unroll
    for (int r = 0; r < 4; ++r)
      xv[r] = *(const u16x4*)(xgt + (l4 * 4 + r) * 1024 + (w * 16 + l15) * 4);
    f32x4 acc[4];
#pragma unroll
    for (int g = 0; g < 4; ++g) acc[g] = (f32x4){0.f, 0.f, 0.f, 0.f};
    // reg slabs 0,1
#pragma unroll
    for (int s = 0; s < 2; ++s) {
      bf16x8 a = *(const bf16x8*)(hrd + l15 * 512 + ((s * 64 + l4 * 16) ^ ((l15 & 7) << 4)));
#pragma unroll
      for (int g = 0; g < 4; ++g)
        acc[g] = __builtin_amdgcn_mfma_f32_16x16x32_bf16(a, breg[s][g], acc[g], 0, 0, 0);
    }
    // LDS slabs 2,3
#pragma unroll
    for (int sl = 0; sl < 2; ++sl) {
      bf16x8 a = *(const bf16x8*)(hrd + l15 * 512 + (((2 + sl) * 64 + l4 * 16) ^ ((l15 & 7) << 4)));
#pragma unroll
      for (int g = 0; g < 4; ++g) {
        bf16x8 bb = *(const bf16x8*)(lds + (w * 8 + sl * 4 + g) * 1024 + l * 16);
        acc[g] = __builtin_amdgcn_mfma_f32_16x16x32_bf16(a, bb, acc[g], 0, 0, 0);
      }
    }
    // streamed slabs 4..7 (one slab's 4 frags live at a time; L2-hit, hidden by 4 waves/SIMD)
#pragma unroll
    for (int s = 4; s < 8; ++s) {
      bf16x8 bsx[4];
#pragma unroll
      for (int g = 0; g < 4; ++g)
        bsx[g] = *(const bf16x8*)(wbase + ((s * 4 + g) * 64 + l) * 8);
      bf16x8 a = *(const bf16x8*)(hrd + l15 * 512 + ((s * 64 + l4 * 16) ^ ((l15 & 7) << 4)));
#pragma unroll
      for (int g = 0; g < 4; ++g)
        acc[g] = __builtin_amdgcn_mfma_f32_16x16x32_bf16(a, bsx[g], acc[g], 0, 0, 0);
    }
    // ---- cell update (lane-local) ----
#pragma unroll
    for (int r = 0; r < 4; ++r) {
      float gi = acc[0][r] + bf2f(xv[r][0]);
      float gf = acc[1][r] + bf2f(xv[r][1]);
      float gg = acc[2][r] + bf2f(xv[r][2]);
      float go = acc[3][r] + bf2f(xv[r][3]);
      float cn = sigf(gf) * cst[r] + sigf(gi) * tanh_(gg);
      cst[r] = cn;
      float hn = sigf(go) * tanh_(cn);
      int row = l4 * 4 + r;
      int hcol = w * 16 + l15;
      if (t < 63)
        *(u16*)(hwr + row * 512 + ((2 * hcol) ^ ((row & 7) << 4))) = f2bf(hn);
      else
        Hf[(size_t)(dir * 1024 + m0 + row) * 256 + hcol] = hn;
    }
    __syncthreads();
  }
}

// ---------------- attention fusion + mean over tweets ----------------
__global__ __launch_bounds__(256) void k_fusion(const float* __restrict__ Hf, const float* __restrict__ IH,
                                                const float* __restrict__ WT, const float* __restrict__ WI,
                                                float* __restrict__ msum) {
  int wv = threadIdx.x >> 6, lane = threadIdx.x & 63;
  float facc[8] = {0.f, 0.f, 0.f, 0.f, 0.f, 0.f, 0.f, 0.f};
  for (int p = 0; p < 8; ++p) {
    int n = blockIdx.x * 32 + wv * 8 + p;
    float th[8], ih[8];
    float ts = 0.f, is = 0.f;
    for (int j = 0; j < 8; ++j) {
      int e = lane * 8 + j;
      float tv = (e < 256) ? Hf[(long long)n * 256 + e] : Hf[(long long)(1024 + n) * 256 + (e - 256)];
      float iv = IH[(long long)n * 512 + e];
      th[j] = tv; ih[j] = iv;
      ts += tv * WT[e];
      is += iv * WI[e];
    }
    for (int off = 32; off > 0; off >>= 1) {
      ts += __shfl_down(ts, off);
      is += __shfl_down(is, off);
    }
    ts = __shfl(ts, 0);
    is = __shfl(is, 0);
    float a0 = 1.f / (1.f + __expf(is - ts));
    float a1 = 1.f - a0;
    for (int j = 0; j < 8; ++j) facc[j] += a0 * th[j] + a1 * ih[j];
  }
  for (int j = 0; j < 8; ++j) atomicAdd(&msum[lane * 8 + j], facc[j]);
}

// ---------------- classifier MLP ----------------
__global__ __launch_bounds__(256) void k_cls(const float* __restrict__ msum, const float* __restrict__ Wc1,
                                             const float* __restrict__ bc1, const float* __restrict__ Wc2,
                                             const float* __restrict__ bc2, float* __restrict__ out) {
  __shared__ float mf[512];
  __shared__ float hdd[512];
  __shared__ float red[2][256];
  int tid = threadIdx.x;
  for (int j = tid; j < 512; j += 256) mf[j] = msum[j] * (1.f / 1024.f);
  __syncthreads();
  for (int j = tid; j < 512; j += 256) {
    const float* wr = Wc1 + (long long)j * 512;
    float s = bc1[j];
    for (int k = 0; k < 512; ++k) s += mf[k] * wr[k];
    hdd[j] = fmaxf(s, 0.f);
  }
  __syncthreads();
  float s0 = 0.f, s1 = 0.f;
  for (int k = tid; k < 512; k += 256) {
    s0 += hdd[k] * Wc2[k];
    s1 += hdd[k] * Wc2[512 + k];
  }
  red[0][tid] = s0;
  red[1][tid] = s1;
  __syncthreads();
  if (tid < 2) {
    float s = 0.f;
    for (int k = 0; k < 256; ++k) s += red[tid][k];
    out[tid] = s + bc2[tid];
  }
}

extern "C" void kernel_launch(void* const* d_in, const int* in_sizes, int n_in,
                              void* d_out, int out_size, void* d_ws, size_t ws_size,
                              hipStream_t stream) {
  const int* tokens = (const int*)d_in[0];
  const float* images = (const float*)d_in[1];
  const float* embed = (const float*)d_in[2];
  const float* Wih_f = (const float*)d_in[3];
  const float* Whh_f = (const float*)d_in[4];
  const float* bih_f = (const float*)d_in[5];
  const float* bhh_f = (const float*)d_in[6];
  const float* Wih_b = (const float*)d_in[7];
  const float* Whh_b = (const float*)d_in[8];
  const float* bih_b = (const float*)d_in[9];
  const float* bhh_b = (const float*)d_in[10];
  const float* Wimg = (const float*)d_in[11];
  const float* bimg = (const float*)d_in[12];
  const float* W_T = (const float*)d_in[13];
  const float* W_I = (const float*)d_in[14];
  const float* Wc1 = (const float*)d_in[15];
  const float* bc1 = (const float*)d_in[16];
  const float* Wc2 = (const float*)d_in[17];
  const float* bc2 = (const float*)d_in[18];
  float* out = (float*)d_out;

  char* ws = (char*)d_ws;
  size_t off = 0;
  auto alloc = [&](size_t bytes) -> void* {
    void* p = ws + off;
    off += (bytes + 255) & ~(size_t)255;
    return p;
  };
  u16* xbf = (u16*)alloc((size_t)M1 * 512 * 2);       // 64 MiB
  u16* xgp = (u16*)alloc((size_t)M1 * 2048 * 2);      // 256 MiB (XGP layout)
  u16* wih_bf = (u16*)alloc((size_t)2048 * 512 * 2);
  u16* wp = (u16*)alloc((size_t)2 * 262144 * 2);      // 1 MiB fragment-packed Whh
  u16* wimg_bf = (u16*)alloc((size_t)512 * 512 * 2);
  float* bias_a = (float*)alloc((size_t)2048 * 4);
  float* hf32 = (float*)alloc((size_t)2048 * 256 * 4);
  u16* im_bf = (u16*)alloc((size_t)1024 * 512 * 2);
  float* im_h = (float*)alloc((size_t)1024 * 512 * 4);
  float* msum = (float*)alloc((size_t)512 * 4);

  hipMemsetAsync(msum, 0, (size_t)512 * 4, stream);

  k_f2bf<<<512, 256, 0, stream>>>(Wih_f, wih_bf, 524288);
  k_f2bf<<<512, 256, 0, stream>>>(Wih_b, wih_bf + 1024 * 512, 524288);
  k_f2bf<<<256, 256, 0, stream>>>(Wimg, wimg_bf, 262144);
  k_prep_wp2<<<2048, 256, 0, stream>>>(Whh_f, Whh_b, wp);
  k_bias<<<8, 256, 0, stream>>>(bih_f, bhh_f, bih_b, bhh_b, bias_a);

  k_gather<<<16384, 256, 0, stream>>>(tokens, embed, xbf);
  k_gemm_xg<<<8192, 256, 0, stream>>>(xbf, wih_bf, bias_a, xgp);

  k_imgmean<<<1024, 256, 0, stream>>>(images, im_bf);
  k_gemm_img<<<dim3(8, 4), 256, 0, stream>>>(im_bf, wimg_bf, bimg, im_h);

  hipFuncSetAttribute((const void*)k_lstm5, hipFuncAttributeMaxDynamicSharedMemorySize, 147456);
  k_lstm5<<<128, 1024, 147456, stream>>>(wp, xgp, hf32);

  k_fusion<<<32, 256, 0, stream>>>(hf32, im_h, W_T, W_I, msum);
  k_cls<<<1, 256, 0, stream>>>(msum, Wc1, bc1, Wc2, bc2, out);
}